// Round 5
// baseline (138.358 us; speedup 1.0000x reference)
//
#include <hip/hip_runtime.h>

// StochaPolicy: out[b,0:32] = phi_m @ w_m.T + b_m ; out[b,32:64] = exp(clip(phi_s @ w_s.T + b_s))
// phi_h[b,k] = exp(-(|x|^2 - 2 x.C_h[k] + |C_h[k]|^2) / (2|sigma_h[k]|))
// B=32768 D=256 K=1024 A=32.
//
// R5: R4 dataflow, but 512-thread blocks (8 waves): wave owns (kc-slice 16) x
// (b-half 32) instead of (kc 16 x b 64). Halves per-wave registers
// (ob 32, acc2 32, a1 8 -> ~125 unified) => 4 waves/SIMD instead of 2,
// doubling cross-wave latency hiding for the GEMM1->exp->GEMM2 dep chain.
// Same fp8 MFMA fragment math, 4-buffer pair-pipelined staging, 1 barrier/pair.

typedef float floatx4 __attribute__((ext_vector_type(4)));
typedef unsigned int u32;
typedef unsigned char u8;

constexpr float LOG2E = 1.4426950408889634f;

__device__ __forceinline__ u32 pk_fp8(float a, float b, float c, float d) {
  u32 v = __builtin_amdgcn_cvt_pk_fp8_f32(a, b, 0u, 0);   // bytes 0,1
  v = __builtin_amdgcn_cvt_pk_fp8_f32(c, d, v, 1);        // bytes 2,3
  return v;
}
__device__ __forceinline__ long mk64(u32 lo, u32 hi) {
  return (long)lo | ((long)hi << 32);
}

// ---------- merged prologue ----------
// blocks 0..511: centers -> fp8 row-major tile-contiguous; a2g[k]=log2e/|sigma|,
//                g2n[k] = -(log2e*0.5/|sigma|)*|C_k|^2
// blocks 512..575: w -> fp8 flat copy  wb[(half*32+a)*1024 + k]
__global__ void prep(const float* __restrict__ mC, const float* __restrict__ mS,
                     const float* __restrict__ sC, const float* __restrict__ sS,
                     const float* __restrict__ mw, const float* __restrict__ sw,
                     u8* __restrict__ Cb, float* __restrict__ a2g,
                     float* __restrict__ g2n, u8* __restrict__ wb)
{
  const int blk = blockIdx.x;
  if (blk < 512) {
    const int wv = threadIdx.x >> 6;
    const int l  = threadIdx.x & 63;
    const int b  = blk * 4 + wv;            // 0..2047 combined center index
    const int half = b >> 10;
    const int k = b & 1023;
    const float* src = (half ? sC : mC) + (size_t)k * 256;
    float4 f = *(const float4*)(src + l * 4);
    float ss = f.x*f.x + f.y*f.y + f.z*f.z + f.w*f.w;
    ((u32*)Cb)[b * 64 + l] = pk_fp8(f.x, f.y, f.z, f.w);
    for (int off = 32; off > 0; off >>= 1) ss += __shfl_down(ss, off, 64);
    if (l == 0) {
      float sig = fabsf((half ? sS : mS)[k]);
      float s2 = LOG2E * 0.5f / sig;
      a2g[b] = 2.f * s2;
      g2n[b] = -s2 * ss;
    }
  } else {
    int i0 = (blk - 512) * 1024 + threadIdx.x * 4;   // 0..65532
    int half = i0 >> 15;
    int rem  = i0 & 32767;
    const float* src = half ? sw : mw;
    float4 f = *(const float4*)(src + rem);
    ((u32*)wb)[i0 >> 2] = pk_fp8(f.x, f.y, f.z, f.w);
  }
}

// ---------- main fused kernel ----------
__global__ __launch_bounds__(512, 4)
void policy_main(const float* __restrict__ obs,
                 const u8* __restrict__ Cb,
                 const float* __restrict__ a2g,
                 const float* __restrict__ g2n,
                 const u8* __restrict__ wb,
                 const float* __restrict__ mbias,
                 const float* __restrict__ sbias,
                 float* __restrict__ out)
{
  // 4 x 16KB staging buffers at 0,16K,32K,48K; x2p at 64K (4352 B).
  // Epilogue red[8][32][68] f32 (69632 B) aliases everything.
  __shared__ __align__(16) char smem[69888];
  float* x2p = (float*)(smem + 65536);
  float* red = (float*)smem;

  const int tid  = threadIdx.x;
  const int lane = tid & 63;
  const int wv   = tid >> 6;        // wave 0..7
  const int c    = lane & 15;
  const int q    = lane >> 4;       // quad 0..3
  const int row0 = blockIdx.x * 64;
  const int kcs  = 16 * (wv >> 1);  // wave's kc slice base [0,16,32,48]
  const int bh   = 32 * (wv & 1);   // wave's b-half base [0,32]
  const int crow = kcs + c;         // center row (GEMM1 A m-index)
  const int kslc = kcs + 4 * q;     // lane's kc sub-slice base within tile
  const int ldl  = tid * 16;        // lane-linear LDS staging offset

  // per-lane global staging offsets (XOR swizzle on 16B slots)
  int goff[2];
  #pragma unroll
  for (int i = 0; i < 2; ++i) {
    int s = i * 512 + tid;          // storage slot 0..1023
    int row = s >> 4;
    int l16 = (s & 15) ^ (row & 15);
    goff[i] = row * 256 + l16 * 16;
  }

  // ---- stage ct0 -> buf0, ct1 -> buf1 (async) ----
  #pragma unroll
  for (int i = 0; i < 2; ++i) {
    __builtin_amdgcn_global_load_lds(
        (const __attribute__((address_space(1))) u32*)(const void*)(Cb + goff[i]),
        (__attribute__((address_space(3))) u32*)(void*)(smem + i * 8192 + ldl), 16, 0, 0);
    __builtin_amdgcn_global_load_lds(
        (const __attribute__((address_space(1))) u32*)(const void*)(Cb + 16384 + goff[i]),
        (__attribute__((address_space(3))) u32*)(void*)(smem + 16384 + i * 8192 + ldl), 16, 0, 0);
  }

  // ---- convert obs tile fp32 -> fp8 into buf3 (49152) + x2 partials ----
  #pragma unroll
  for (int i = 0; i < 2; ++i) {
    int s = i * 512 + tid;
    int row = s >> 4;
    int s16 = s & 15;
    int l16 = s16 ^ (row & 15);
    const float* src = obs + (size_t)(row0 + row) * 256 + l16 * 16;
    float4 f0 = ((const float4*)src)[0];
    float4 f1 = ((const float4*)src)[1];
    float4 f2 = ((const float4*)src)[2];
    float4 f3 = ((const float4*)src)[3];
    uint4 pk;
    pk.x = pk_fp8(f0.x, f0.y, f0.z, f0.w);
    pk.y = pk_fp8(f1.x, f1.y, f1.z, f1.w);
    pk.z = pk_fp8(f2.x, f2.y, f2.z, f2.w);
    pk.w = pk_fp8(f3.x, f3.y, f3.z, f3.w);
    *(uint4*)(smem + 49152 + s * 16) = pk;
    float p = f0.x*f0.x + f0.y*f0.y + f0.z*f0.z + f0.w*f0.w
            + f1.x*f1.x + f1.y*f1.y + f1.z*f1.z + f1.w*f1.w
            + f2.x*f2.x + f2.y*f2.y + f2.z*f2.z + f2.w*f2.w
            + f3.x*f3.x + f3.y*f3.y + f3.z*f3.z + f3.w*f3.w;
    x2p[row * 16 + s16] = p;
  }
  __syncthreads();   // obs tile + partials visible; ct0/ct1 staging drained

  // ---- preload obs B-fragments from buf3: ob[nt][ks], rows bh+nt*16+c ----
  long ob[2][8];                    // 32 VGPRs (MFMA operands)
  #pragma unroll
  for (int nt = 0; nt < 2; ++nt) {
    const int row = bh + nt * 16 + c;
    #pragma unroll
    for (int ks = 0; ks < 8; ++ks) {
      int cc8 = 4 * ks + q;
      int s16 = (cc8 >> 1) ^ (row & 15);
      ob[nt][ks] = *(const long*)(smem + 49152 + row * 256 + s16 * 16 + (q & 1) * 8);
    }
  }
  if (tid < 64) {
    float s = 0.f;
    #pragma unroll
    for (int j = 0; j < 16; j += 4) {
      float4 a = *(const float4*)(x2p + tid * 16 + j);
      s += a.x + a.y + a.z + a.w;
    }
    x2p[1024 + tid] = s;
  }
  __syncthreads();   // buf3 frag reads done (pair0 stages into it); x2 sums visible

  float hx2[2];
  #pragma unroll
  for (int nt = 0; nt < 2; ++nt) hx2[nt] = 0.5f * x2p[1024 + bh + nt * 16 + c];

  // GEMM1 LDS read offsets within a buffer (loop-invariant)
  int voff[8];
  #pragma unroll
  for (int ks = 0; ks < 8; ++ks) {
    int cc8 = 4 * ks + q;
    int s16 = (cc8 >> 1) ^ (crow & 15);
    voff[ks] = crow * 256 + s16 * 16 + (q & 1) * 8;
  }

  const floatx4 Z4 = {0.f, 0.f, 0.f, 0.f};
  floatx4 acc2m[2][2], acc2s[2][2];   // 16+16 regs, static indexing only
  #pragma unroll
  for (int a2i = 0; a2i < 2; ++a2i)
    #pragma unroll
    for (int nt = 0; nt < 2; ++nt) {
      acc2m[a2i][nt] = Z4;
      acc2s[a2i][nt] = Z4;
    }

  int cA = 0, cB = 16384, nA = 32768, nB = 49152;  // uniform (SGPR) buffer bases
  u32 pE[2], pc[2];

#define PAIR_BODY(ACC, HB)                                                              \
  {                                                                                     \
    const int cte = 2 * pr;                                                             \
    if (pr < 15) {                                                                      \
      const u8* g0 = Cb + (size_t)(cte + 2) * 16384;                                    \
      _Pragma("unroll")                                                                 \
      for (int i = 0; i < 2; ++i) {                                                     \
        __builtin_amdgcn_global_load_lds(                                               \
            (const __attribute__((address_space(1))) u32*)(const void*)(g0 + goff[i]),  \
            (__attribute__((address_space(3))) u32*)(void*)(smem + nA + i * 8192 + ldl),\
            16, 0, 0);                                                                  \
        __builtin_amdgcn_global_load_lds(                                               \
            (const __attribute__((address_space(1))) u32*)(const void*)(g0 + 16384 + goff[i]), \
            (__attribute__((address_space(3))) u32*)(void*)(smem + nB + i * 8192 + ldl),\
            16, 0, 0);                                                                  \
      }                                                                                 \
    }                                                                                   \
    float4 a2e = *(const float4*)(a2g + cte * 64 + kslc);                               \
    float4 g2e = *(const float4*)(g2n + cte * 64 + kslc);                               \
    float4 a2o = *(const float4*)(a2g + cte * 64 + 64 + kslc);                          \
    float4 g2o = *(const float4*)(g2n + cte * 64 + 64 + kslc);                          \
    const int kbE = (cte & 15) * 64 + kslc;                                             \
    const u8* wr0 = wb + (size_t)(HB + c) * 1024 + kbE;                                 \
    const u8* wr1 = wb + (size_t)(HB + 16 + c) * 1024 + kbE;                            \
    u32 w0lo = *(const u32*)wr0, w0hi = *(const u32*)(wr0 + 64);                        \
    u32 w1lo = *(const u32*)wr1, w1hi = *(const u32*)(wr1 + 64);                        \
    floatx4 a1[2];                                                                      \
    { long cf = *(const long*)(smem + cA + voff[0]);                                    \
      a1[0] = __builtin_amdgcn_mfma_f32_16x16x32_fp8_fp8(cf, ob[0][0], Z4, 0, 0, 0);    \
      a1[1] = __builtin_amdgcn_mfma_f32_16x16x32_fp8_fp8(cf, ob[1][0], Z4, 0, 0, 0); }  \
    _Pragma("unroll")                                                                   \
    for (int ks = 1; ks < 8; ++ks) {                                                    \
      long cf = *(const long*)(smem + cA + voff[ks]);                                   \
      a1[0] = __builtin_amdgcn_mfma_f32_16x16x32_fp8_fp8(cf, ob[0][ks], a1[0], 0, 0, 0);\
      a1[1] = __builtin_amdgcn_mfma_f32_16x16x32_fp8_fp8(cf, ob[1][ks], a1[1], 0, 0, 0);\
    }                                                                                   \
    _Pragma("unroll")                                                                   \
    for (int nt = 0; nt < 2; ++nt) {                                                    \
      float t0 = a1[nt][0] - hx2[nt], t1 = a1[nt][1] - hx2[nt];                         \
      float t2 = a1[nt][2] - hx2[nt], t3 = a1[nt][3] - hx2[nt];                         \
      pE[nt] = pk_fp8(__builtin_amdgcn_exp2f(fmaf(a2e.x, t0, g2e.x)),                   \
                      __builtin_amdgcn_exp2f(fmaf(a2e.y, t1, g2e.y)),                   \
                      __builtin_amdgcn_exp2f(fmaf(a2e.z, t2, g2e.z)),                   \
                      __builtin_amdgcn_exp2f(fmaf(a2e.w, t3, g2e.w)));                  \
    }                                                                                   \
    { long cf = *(const long*)(smem + cB + voff[0]);                                    \
      a1[0] = __builtin_amdgcn_mfma_f32_16x16x32_fp8_fp8(cf, ob[0][0], Z4, 0, 0, 0);    \
      a1[1] = __builtin_amdgcn_mfma_f32_16x16x32_fp8_fp8(cf, ob[1][0], Z4, 0, 0, 0); }  \
    _Pragma("unroll")                                                                   \
    for (int ks = 1; ks < 8; ++ks) {                                                    \
      long cf = *(const long*)(smem + cB + voff[ks]);                                   \
      a1[0] = __builtin_amdgcn_mfma_f32_16x16x32_fp8_fp8(cf, ob[0][ks], a1[0], 0, 0, 0);\
      a1[1] = __builtin_amdgcn_mfma_f32_16x16x32_fp8_fp8(cf, ob[1][ks], a1[1], 0, 0, 0);\
    }                                                                                   \
    _Pragma("unroll")                                                                   \
    for (int nt = 0; nt < 2; ++nt) {                                                    \
      float t0 = a1[nt][0] - hx2[nt], t1 = a1[nt][1] - hx2[nt];                         \
      float t2 = a1[nt][2] - hx2[nt], t3 = a1[nt][3] - hx2[nt];                         \
      pc[nt] = pk_fp8(__builtin_amdgcn_exp2f(fmaf(a2o.x, t0, g2o.x)),                   \
                      __builtin_amdgcn_exp2f(fmaf(a2o.y, t1, g2o.y)),                   \
                      __builtin_amdgcn_exp2f(fmaf(a2o.z, t2, g2o.z)),                   \
                      __builtin_amdgcn_exp2f(fmaf(a2o.w, t3, g2o.w)));                  \
    }                                                                                   \
    { long wA0 = mk64(w0lo, w0hi), wA1 = mk64(w1lo, w1hi);                              \
      _Pragma("unroll")                                                                 \
      for (int nt = 0; nt < 2; ++nt) {                                                  \
        long pb = mk64(pE[nt], pc[nt]);                                                 \
        ACC[0][nt] = __builtin_amdgcn_mfma_f32_16x16x32_fp8_fp8(wA0, pb, ACC[0][nt], 0, 0, 0); \
        ACC[1][nt] = __builtin_amdgcn_mfma_f32_16x16x32_fp8_fp8(wA1, pb, ACC[1][nt], 0, 0, 0); \
      } }                                                                               \
    __syncthreads();                                                                    \
    { int t_ = cA; cA = nA; nA = t_; t_ = cB; cB = nB; nB = t_; }                       \
  }

  for (int pr = 0; pr < 8; ++pr) PAIR_BODY(acc2m, 0)
  for (int pr = 8; pr < 16; ++pr) PAIR_BODY(acc2s, 32)
#undef PAIR_BODY

  // ---- epilogue: cross-wave reduction of per-wave partial out tiles ----
  // red[wv][bl=32][a=68pad]; lane(c,q) reg r holds a = h*32+a2i*16+4q+r, bl = nt*16+c
  {
    float* myr = red + wv * 2176;
    #pragma unroll
    for (int a2i = 0; a2i < 2; ++a2i)
      #pragma unroll
      for (int nt = 0; nt < 2; ++nt) {
        *(floatx4*)(myr + (nt * 16 + c) * 68 + a2i * 16 + 4 * q)      = acc2m[a2i][nt];
        *(floatx4*)(myr + (nt * 16 + c) * 68 + 32 + a2i * 16 + 4 * q) = acc2s[a2i][nt];
      }
  }
  __syncthreads();

  // b-half 0 partials: waves {0,2,4,6}; b-half 1: waves {1,3,5,7}
  #pragma unroll
  for (int i = 0; i < 8; ++i) {
    int idx = tid + 512 * i;        // 0..4095
    int a = idx & 63;
    int b = idx >> 6;
    int bl = b & 31;
    int w0 = (b >> 5);              // 0 or 1
    float v = red[(w0    ) * 2176 + bl * 68 + a] + red[(w0 + 2) * 2176 + bl * 68 + a] +
              red[(w0 + 4) * 2176 + bl * 68 + a] + red[(w0 + 6) * 2176 + bl * 68 + a];
    if (a < 32) {
      v += mbias[a];
    } else {
      v += sbias[a - 32];
      v = fminf(fmaxf(v, -20.f), 2.f);
      v = __builtin_amdgcn_exp2f(v * LOG2E);
    }
    out[(size_t)(row0 + b) * 64 + a] = v;
  }
}

extern "C" void kernel_launch(void* const* d_in, const int* in_sizes, int n_in,
                              void* d_out, int out_size, void* d_ws, size_t ws_size,
                              hipStream_t stream) {
  const float* obs = (const float*)d_in[0];
  const float* mC  = (const float*)d_in[1];
  const float* mS  = (const float*)d_in[2];
  const float* mW  = (const float*)d_in[3];
  const float* mB  = (const float*)d_in[4];
  const float* sC  = (const float*)d_in[5];
  const float* sS  = (const float*)d_in[6];
  const float* sW  = (const float*)d_in[7];
  const float* sB  = (const float*)d_in[8];
  float* out = (float*)d_out;

  // workspace: Cb[2048*256] fp8 (512KB) | a2g[2048] f32 | g2n[2048] f32 | wb[65536] fp8
  u8*    Cb  = (u8*)d_ws;
  float* a2g = (float*)((char*)d_ws + 2048 * 256);
  float* g2n = a2g + 2048;
  u8*    wb  = (u8*)(g2n + 2048);

  prep<<<576, 256, 0, stream>>>(mC, mS, sC, sS, mW, sW, Cb, a2g, g2n, wb);
  policy_main<<<512, 512, 0, stream>>>(obs, Cb, a2g, g2n, wb, mB, sB, out);
}

// Round 6
// 130.123 us; speedup vs baseline: 1.0633x; 1.0633x over previous
//
#include <hip/hip_runtime.h>

// StochaPolicy: out[b,0:32] = phi_m @ w_m.T + b_m ; out[b,32:64] = exp(clip(phi_s @ w_s.T + b_s))
// phi_h[b,k] = exp(-(|x|^2 - 2 x.C_h[k] + |C_h[k]|^2) / (2|sigma_h[k]|))
// B=32768 D=256 K=1024 A=32.
//
// R6: barrier-free K-loop. R5 disproved the occupancy theory (2x occupancy,
// slower): the stall is lockstep phases — all waves do GEMM1, then all do exp,
// re-aligned by a per-pair barrier. Fix: centers are per-wave-private, so drop
// LDS staging entirely. prep writes centers in lane-contiguous fragment order
// (lane's 8 K-chunks = 64B contiguous); each wave prefetches its fragments
// global->VGPR (4 x dwordx4 / lane / tile, L2-resident) one pair ahead.
// K-loop: ZERO LDS, ZERO barriers -> waves free-run, phases decorrelate,
// exp/pack of one wave overlaps MFMA burst of another (m114 co-scheduling).
// LDS only in prologue (obs tile) and epilogue (cross-wave reduce).

typedef float floatx4 __attribute__((ext_vector_type(4)));
typedef long longx2 __attribute__((ext_vector_type(2)));
typedef unsigned int u32;
typedef unsigned char u8;

constexpr float LOG2E = 1.4426950408889634f;

__device__ __forceinline__ u32 pk_fp8(float a, float b, float c, float d) {
  u32 v = __builtin_amdgcn_cvt_pk_fp8_f32(a, b, 0u, 0);   // bytes 0,1
  v = __builtin_amdgcn_cvt_pk_fp8_f32(c, d, v, 1);        // bytes 2,3
  return v;
}
__device__ __forceinline__ long mk64(u32 lo, u32 hi) {
  return (long)lo | ((long)hi << 32);
}

// ---------- merged prologue ----------
// blocks 0..511 (4 centers each): centers -> fp8 in LANE-FRAGMENT order:
//   Cb2[ct*16384 + wv*4096 + (q*16+c)*64 + ks*8 + r] = C_row[32ks+8q+r..+4]
//   (ct=b>>6, row=b&63, wv=row>>4, c=row&15) — a lane's 8 GEMM1 chunks are
//   64 contiguous bytes. Also a2g[k]=log2e/|sigma|, g2n[k]=-(log2e*.5/|s|)*|C|^2.
// blocks 512..575: w -> fp8 flat copy  wb[(half*32+a)*1024 + k]
__global__ void prep(const float* __restrict__ mC, const float* __restrict__ mS,
                     const float* __restrict__ sC, const float* __restrict__ sS,
                     const float* __restrict__ mw, const float* __restrict__ sw,
                     u8* __restrict__ Cb2, float* __restrict__ a2g,
                     float* __restrict__ g2n, u8* __restrict__ wb)
{
  const int blk = blockIdx.x;
  if (blk < 512) {
    const int wq = threadIdx.x >> 6;
    const int t  = threadIdx.x & 63;
    const int b  = blk * 4 + wq;            // 0..2047 combined center index
    const int half = b >> 10;
    const int k = b & 1023;
    const float* src = (half ? sC : mC) + (size_t)k * 256;
    float4 f = *(const float4*)(src + t * 4);
    float ss = f.x*f.x + f.y*f.y + f.z*f.z + f.w*f.w;
    const int ct = b >> 6, row = b & 63;
    const int wvv = row >> 4, cc = row & 15;
    const int ks = t >> 3, qq = (t >> 1) & 3, rr = (t & 1) * 4;
    *(u32*)(Cb2 + (size_t)ct * 16384 + wvv * 4096 + (qq * 16 + cc) * 64 + ks * 8 + rr) =
        pk_fp8(f.x, f.y, f.z, f.w);
    for (int off = 32; off > 0; off >>= 1) ss += __shfl_down(ss, off, 64);
    if (t == 0) {
      float sig = fabsf((half ? sS : mS)[k]);
      float s2 = LOG2E * 0.5f / sig;
      a2g[b] = 2.f * s2;
      g2n[b] = -s2 * ss;
    }
  } else {
    int i0 = (blk - 512) * 1024 + threadIdx.x * 4;   // 0..65532
    int half = i0 >> 15;
    int rem  = i0 & 32767;
    const float* src = half ? sw : mw;
    float4 f = *(const float4*)(src + rem);
    ((u32*)wb)[i0 >> 2] = pk_fp8(f.x, f.y, f.z, f.w);
  }
}

// ---------- main fused kernel ----------
__global__ __launch_bounds__(256, 2)
void policy_main(const float* __restrict__ obs,
                 const u8* __restrict__ Cb2,
                 const float* __restrict__ a2g,
                 const float* __restrict__ g2n,
                 const u8* __restrict__ wb,
                 const float* __restrict__ mbias,
                 const float* __restrict__ sbias,
                 float* __restrict__ out)
{
  // LDS: prologue obs fp8 tile [0,16384) + x2p [16384,20736).
  // Epilogue red[4][64][68] f32 (69632 B) aliases from 0.
  __shared__ __align__(16) char smem[69888];
  float* x2p = (float*)(smem + 16384);
  float* red = (float*)smem;

  const int tid  = threadIdx.x;
  const int lane = tid & 63;
  const int wv   = tid >> 6;        // wave 0..3 : kc slice [16wv,16wv+16)
  const int c    = lane & 15;
  const int q    = lane >> 4;       // quad 0..3
  const int row0 = blockIdx.x * 64;
  const int kslc = 16 * wv + 4 * q; // lane's kc sub-slice base within tile
  const int cfo  = tid * 64;        // = wv*4096 + lane*64 : lane's fragment bytes

  // ---- prefetch pair 0 center fragments (tiles 0,1) into regs ----
  long cfPA[8], cfPB[8], cfQA[8], cfQB[8];
  #pragma unroll
  for (int i = 0; i < 4; ++i) {
    longx2 t0 = *(const longx2*)(Cb2 + cfo + i * 16);
    cfPA[2 * i] = t0.x; cfPA[2 * i + 1] = t0.y;
    longx2 t1 = *(const longx2*)(Cb2 + 16384 + cfo + i * 16);
    cfPB[2 * i] = t1.x; cfPB[2 * i + 1] = t1.y;
  }

  // ---- convert obs tile fp32 -> fp8 into LDS (XOR-swizzled) + x2 partials ----
  #pragma unroll
  for (int i = 0; i < 4; ++i) {
    int s = i * 256 + tid;          // 16B slot 0..1023
    int row = s >> 4;
    int s16 = s & 15;
    int l16 = s16 ^ (row & 15);
    const float* src = obs + (size_t)(row0 + row) * 256 + l16 * 16;
    float4 f0 = ((const float4*)src)[0];
    float4 f1 = ((const float4*)src)[1];
    float4 f2 = ((const float4*)src)[2];
    float4 f3 = ((const float4*)src)[3];
    uint4 pk;
    pk.x = pk_fp8(f0.x, f0.y, f0.z, f0.w);
    pk.y = pk_fp8(f1.x, f1.y, f1.z, f1.w);
    pk.z = pk_fp8(f2.x, f2.y, f2.z, f2.w);
    pk.w = pk_fp8(f3.x, f3.y, f3.z, f3.w);
    *(uint4*)(smem + s * 16) = pk;
    float p = f0.x*f0.x + f0.y*f0.y + f0.z*f0.z + f0.w*f0.w
            + f1.x*f1.x + f1.y*f1.y + f1.z*f1.z + f1.w*f1.w
            + f2.x*f2.x + f2.y*f2.y + f2.z*f2.z + f2.w*f2.w
            + f3.x*f3.x + f3.y*f3.y + f3.z*f3.z + f3.w*f3.w;
    x2p[row * 16 + s16] = p;
  }
  __syncthreads();   // obs tile + partials visible

  // ---- preload obs B-fragments: ob[nt][ks] = obs[b=nt*16+c][d=32ks+8q..+8] ----
  long ob[4][8];                    // 64 regs (MFMA operands)
  #pragma unroll
  for (int nt = 0; nt < 4; ++nt) {
    const int row = nt * 16 + c;
    #pragma unroll
    for (int ks = 0; ks < 8; ++ks) {
      int cc8 = 4 * ks + q;
      int s16 = (cc8 >> 1) ^ (row & 15);
      ob[nt][ks] = *(const long*)(smem + row * 256 + s16 * 16 + (q & 1) * 8);
    }
  }
  if (tid < 64) {
    float s = 0.f;
    #pragma unroll
    for (int j = 0; j < 16; j += 4) {
      float4 a = *(const float4*)(x2p + tid * 16 + j);
      s += a.x + a.y + a.z + a.w;
    }
    x2p[1024 + tid] = s;
  }
  __syncthreads();   // x2 sums visible (last barrier before epilogue)

  float hx2[4];
  #pragma unroll
  for (int nt = 0; nt < 4; ++nt) hx2[nt] = 0.5f * x2p[1024 + nt * 16 + c];

  const floatx4 Z4 = {0.f, 0.f, 0.f, 0.f};
  floatx4 acc2m[2][4], acc2s[2][4];   // 64 regs (AGPR), static indexing only
  #pragma unroll
  for (int a2i = 0; a2i < 2; ++a2i)
    #pragma unroll
    for (int nt = 0; nt < 4; ++nt) {
      acc2m[a2i][nt] = Z4;
      acc2s[a2i][nt] = Z4;
    }

  u32 pE[4], pc[4];

  // ---- K-loop: 16 pairs, NO barriers, NO LDS. CUR consumed, NXT prefetched. ----
#define PAIR_BODY(pr, CA, CB, NA, NB, ACC, HB)                                          \
  {                                                                                     \
    const int cte = 2 * (pr);                                                           \
    if ((pr) < 15) {                                                                    \
      const u8* g0 = Cb2 + (size_t)(cte + 2) * 16384 + cfo;                             \
      _Pragma("unroll")                                                                 \
      for (int i = 0; i < 4; ++i) {                                                     \
        longx2 t0 = *(const longx2*)(g0 + i * 16);                                      \
        NA[2 * i] = t0.x; NA[2 * i + 1] = t0.y;                                         \
        longx2 t1 = *(const longx2*)(g0 + 16384 + i * 16);                              \
        NB[2 * i] = t1.x; NB[2 * i + 1] = t1.y;                                         \
      }                                                                                 \
    }                                                                                   \
    float4 a2e = *(const float4*)(a2g + cte * 64 + kslc);                               \
    float4 g2e = *(const float4*)(g2n + cte * 64 + kslc);                               \
    float4 a2o = *(const float4*)(a2g + cte * 64 + 64 + kslc);                          \
    float4 g2o = *(const float4*)(g2n + cte * 64 + 64 + kslc);                          \
    const int kbE = (cte & 15) * 64 + kslc;                                             \
    const u8* wr0 = wb + (size_t)((HB) + c) * 1024 + kbE;                               \
    const u8* wr1 = wb + (size_t)((HB) + 16 + c) * 1024 + kbE;                          \
    u32 w0lo = *(const u32*)wr0, w0hi = *(const u32*)(wr0 + 64);                        \
    u32 w1lo = *(const u32*)wr1, w1hi = *(const u32*)(wr1 + 64);                        \
    floatx4 a1[4];                                                                      \
    a1[0] = __builtin_amdgcn_mfma_f32_16x16x32_fp8_fp8(CA[0], ob[0][0], Z4, 0, 0, 0);   \
    a1[1] = __builtin_amdgcn_mfma_f32_16x16x32_fp8_fp8(CA[0], ob[1][0], Z4, 0, 0, 0);   \
    a1[2] = __builtin_amdgcn_mfma_f32_16x16x32_fp8_fp8(CA[0], ob[2][0], Z4, 0, 0, 0);   \
    a1[3] = __builtin_amdgcn_mfma_f32_16x16x32_fp8_fp8(CA[0], ob[3][0], Z4, 0, 0, 0);   \
    _Pragma("unroll")                                                                   \
    for (int ks = 1; ks < 8; ++ks) {                                                    \
      a1[0] = __builtin_amdgcn_mfma_f32_16x16x32_fp8_fp8(CA[ks], ob[0][ks], a1[0], 0, 0, 0); \
      a1[1] = __builtin_amdgcn_mfma_f32_16x16x32_fp8_fp8(CA[ks], ob[1][ks], a1[1], 0, 0, 0); \
      a1[2] = __builtin_amdgcn_mfma_f32_16x16x32_fp8_fp8(CA[ks], ob[2][ks], a1[2], 0, 0, 0); \
      a1[3] = __builtin_amdgcn_mfma_f32_16x16x32_fp8_fp8(CA[ks], ob[3][ks], a1[3], 0, 0, 0); \
    }                                                                                   \
    _Pragma("unroll")                                                                   \
    for (int nt = 0; nt < 4; ++nt) {                                                    \
      float t0 = a1[nt][0] - hx2[nt], t1 = a1[nt][1] - hx2[nt];                         \
      float t2 = a1[nt][2] - hx2[nt], t3 = a1[nt][3] - hx2[nt];                         \
      pE[nt] = pk_fp8(__builtin_amdgcn_exp2f(fmaf(a2e.x, t0, g2e.x)),                   \
                      __builtin_amdgcn_exp2f(fmaf(a2e.y, t1, g2e.y)),                   \
                      __builtin_amdgcn_exp2f(fmaf(a2e.z, t2, g2e.z)),                   \
                      __builtin_amdgcn_exp2f(fmaf(a2e.w, t3, g2e.w)));                  \
    }                                                                                   \
    a1[0] = __builtin_amdgcn_mfma_f32_16x16x32_fp8_fp8(CB[0], ob[0][0], Z4, 0, 0, 0);   \
    a1[1] = __builtin_amdgcn_mfma_f32_16x16x32_fp8_fp8(CB[0], ob[1][0], Z4, 0, 0, 0);   \
    a1[2] = __builtin_amdgcn_mfma_f32_16x16x32_fp8_fp8(CB[0], ob[2][0], Z4, 0, 0, 0);   \
    a1[3] = __builtin_amdgcn_mfma_f32_16x16x32_fp8_fp8(CB[0], ob[3][0], Z4, 0, 0, 0);   \
    _Pragma("unroll")                                                                   \
    for (int ks = 1; ks < 8; ++ks) {                                                    \
      a1[0] = __builtin_amdgcn_mfma_f32_16x16x32_fp8_fp8(CB[ks], ob[0][ks], a1[0], 0, 0, 0); \
      a1[1] = __builtin_amdgcn_mfma_f32_16x16x32_fp8_fp8(CB[ks], ob[1][ks], a1[1], 0, 0, 0); \
      a1[2] = __builtin_amdgcn_mfma_f32_16x16x32_fp8_fp8(CB[ks], ob[2][ks], a1[2], 0, 0, 0); \
      a1[3] = __builtin_amdgcn_mfma_f32_16x16x32_fp8_fp8(CB[ks], ob[3][ks], a1[3], 0, 0, 0); \
    }                                                                                   \
    _Pragma("unroll")                                                                   \
    for (int nt = 0; nt < 4; ++nt) {                                                    \
      float t0 = a1[nt][0] - hx2[nt], t1 = a1[nt][1] - hx2[nt];                         \
      float t2 = a1[nt][2] - hx2[nt], t3 = a1[nt][3] - hx2[nt];                         \
      pc[nt] = pk_fp8(__builtin_amdgcn_exp2f(fmaf(a2o.x, t0, g2o.x)),                   \
                      __builtin_amdgcn_exp2f(fmaf(a2o.y, t1, g2o.y)),                   \
                      __builtin_amdgcn_exp2f(fmaf(a2o.z, t2, g2o.z)),                   \
                      __builtin_amdgcn_exp2f(fmaf(a2o.w, t3, g2o.w)));                  \
    }                                                                                   \
    { long wA0 = mk64(w0lo, w0hi), wA1 = mk64(w1lo, w1hi);                              \
      _Pragma("unroll")                                                                 \
      for (int nt = 0; nt < 4; ++nt) {                                                  \
        long pb = mk64(pE[nt], pc[nt]);                                                 \
        ACC[0][nt] = __builtin_amdgcn_mfma_f32_16x16x32_fp8_fp8(wA0, pb, ACC[0][nt], 0, 0, 0); \
        ACC[1][nt] = __builtin_amdgcn_mfma_f32_16x16x32_fp8_fp8(wA1, pb, ACC[1][nt], 0, 0, 0); \
      } }                                                                               \
  }

  for (int pr = 0; pr < 8; pr += 2) {
    PAIR_BODY(pr,     cfPA, cfPB, cfQA, cfQB, acc2m, 0)
    PAIR_BODY(pr + 1, cfQA, cfQB, cfPA, cfPB, acc2m, 0)
  }
  for (int pr = 8; pr < 16; pr += 2) {
    PAIR_BODY(pr,     cfPA, cfPB, cfQA, cfQB, acc2s, 32)
    PAIR_BODY(pr + 1, cfQA, cfQB, cfPA, cfPB, acc2s, 32)
  }
#undef PAIR_BODY

  // ---- epilogue: cross-wave reduction (red aliases obs LDS; K-loop reads no LDS) ----
  // red[wv][b=64][a=68pad]; lane(c,q) reg r holds a = h*32+a2i*16+4q+r, b = nt*16+c
  {
    float* myr = red + wv * 4352;
    #pragma unroll
    for (int a2i = 0; a2i < 2; ++a2i)
      #pragma unroll
      for (int nt = 0; nt < 4; ++nt) {
        *(floatx4*)(myr + (nt * 16 + c) * 68 + a2i * 16 + 4 * q)      = acc2m[a2i][nt];
        *(floatx4*)(myr + (nt * 16 + c) * 68 + 32 + a2i * 16 + 4 * q) = acc2s[a2i][nt];
      }
  }
  __syncthreads();

  #pragma unroll
  for (int i = 0; i < 16; ++i) {
    int idx = tid + 256 * i;        // 0..4095
    int a = idx & 63;
    int b = idx >> 6;
    float v = red[b * 68 + a] + red[4352 + b * 68 + a] +
              red[8704 + b * 68 + a] + red[13056 + b * 68 + a];
    if (a < 32) {
      v += mbias[a];
    } else {
      v += sbias[a - 32];
      v = fminf(fmaxf(v, -20.f), 2.f);
      v = __builtin_amdgcn_exp2f(v * LOG2E);
    }
    out[(size_t)(row0 + b) * 64 + a] = v;
  }
}

extern "C" void kernel_launch(void* const* d_in, const int* in_sizes, int n_in,
                              void* d_out, int out_size, void* d_ws, size_t ws_size,
                              hipStream_t stream) {
  const float* obs = (const float*)d_in[0];
  const float* mC  = (const float*)d_in[1];
  const float* mS  = (const float*)d_in[2];
  const float* mW  = (const float*)d_in[3];
  const float* mB  = (const float*)d_in[4];
  const float* sC  = (const float*)d_in[5];
  const float* sS  = (const float*)d_in[6];
  const float* sW  = (const float*)d_in[7];
  const float* sB  = (const float*)d_in[8];
  float* out = (float*)d_out;

  // workspace: Cb2[2048*256] fp8 (512KB) | a2g[2048] f32 | g2n[2048] f32 | wb[65536] fp8
  u8*    Cb2 = (u8*)d_ws;
  float* a2g = (float*)((char*)d_ws + 2048 * 256);
  float* g2n = a2g + 2048;
  u8*    wb  = (u8*)(g2n + 2048);

  prep<<<576, 256, 0, stream>>>(mC, mS, sC, sS, mW, sW, Cb2, a2g, g2n, wb);
  policy_main<<<512, 256, 0, stream>>>(obs, Cb2, a2g, g2n, wb, mB, sB, out);
}

// Round 7
// 128.169 us; speedup vs baseline: 1.0795x; 1.0153x over previous
//
#include <hip/hip_runtime.h>

// StochaPolicy: out[b,0:32] = phi_m @ w_m.T + b_m ; out[b,32:64] = exp(clip(phi_s @ w_s.T + b_s))
// phi_h[b,k] = exp(-(|x|^2 - 2 x.C_h[k] + |C_h[k]|^2) / (2|sigma_h[k]|))
// B=32768 D=256 K=1024 A=32.
//
// R7: R6's zero-barrier/zero-LDS K-loop, with GEMM1 switched fp8->i8
// (mfma_i32_16x16x64_i8, 2x MAC rate): GEMM1 MFMA count halves, floor
// 18.6 -> 10.8 us. Inputs quantized to i8 at global scale 127/5 (clamped);
// integer |x|^2,|c|^2 folded into exp constants (r = s^2 * (x2i - 2dot + c2i)).
// GEMM2 unchanged (phi fp8 from 16x16 C-layout -> B-operand trick; C/D layout
// is dtype-independent so the trick survives the i8 switch).

typedef float floatx4 __attribute__((ext_vector_type(4)));
typedef int   intx4  __attribute__((ext_vector_type(4)));
typedef unsigned int u32;
typedef unsigned char u8;

constexpr float LOG2E = 1.4426950408889634f;
constexpr float QS    = 25.4f;                 // 127/5 quant multiplier
constexpr float SINV2 = (5.0f / 127.0f) * (5.0f / 127.0f);

__device__ __forceinline__ u32 pk_fp8(float a, float b, float c, float d) {
  u32 v = __builtin_amdgcn_cvt_pk_fp8_f32(a, b, 0u, 0);   // bytes 0,1
  v = __builtin_amdgcn_cvt_pk_fp8_f32(c, d, v, 1);        // bytes 2,3
  return v;
}
__device__ __forceinline__ long mk64(u32 lo, u32 hi) {
  return (long)lo | ((long)hi << 32);
}
__device__ __forceinline__ int q8(float x) {
  return (int)rintf(fminf(fmaxf(x * QS, -127.f), 127.f));
}
__device__ __forceinline__ u32 pk_i8(int a, int b, int c, int d) {
  return (u32)(a & 255) | ((u32)(b & 255) << 8) | ((u32)(c & 255) << 16) | ((u32)(d & 255) << 24);
}

// ---------- merged prologue ----------
// blocks 0..511 (4 centers each): centers -> i8 in lane-fragment order for
// K=64 MFMA: Cb2[ct*16384 + wv*4096 + (16q+c)*64 + 16ks + j] = q8(C[16wv+c][64ks+16q+j])
// (ct=b>>6, row=b&63). Also a2g[k]=2*t2, g2n[k]=-t2*c2i with
// t2 = s^2*log2e/(2|sigma|), c2i = sum of squared quantized center.
// blocks 512..575: w -> fp8 flat copy  wb[(half*32+a)*1024 + k]
__global__ void prep(const float* __restrict__ mC, const float* __restrict__ mS,
                     const float* __restrict__ sC, const float* __restrict__ sS,
                     const float* __restrict__ mw, const float* __restrict__ sw,
                     u8* __restrict__ Cb2, float* __restrict__ a2g,
                     float* __restrict__ g2n, u8* __restrict__ wb)
{
  const int blk = blockIdx.x;
  if (blk < 512) {
    const int wq = threadIdx.x >> 6;
    const int t  = threadIdx.x & 63;
    const int b  = blk * 4 + wq;            // 0..2047 combined center index
    const int half = b >> 10;
    const int k = b & 1023;
    const float* src = (half ? sC : mC) + (size_t)k * 256;
    float4 f = *(const float4*)(src + t * 4);
    int i0 = q8(f.x), i1 = q8(f.y), i2 = q8(f.z), i3 = q8(f.w);
    const int ct = b >> 6, row = b & 63;
    const int wvv = row >> 4, cc = row & 15;
    const int ks = t >> 4, qq = (t >> 2) & 3, j0 = (t & 3) * 4;
    *(u32*)(Cb2 + (size_t)ct * 16384 + wvv * 4096 + (16 * qq + cc) * 64 + 16 * ks + j0) =
        pk_i8(i0, i1, i2, i3);
    int is = i0 * i0 + i1 * i1 + i2 * i2 + i3 * i3;
    for (int off = 32; off > 0; off >>= 1) is += __shfl_down(is, off, 64);
    if (t == 0) {
      float sig = fabsf((half ? sS : mS)[k]);
      float t2 = SINV2 * LOG2E * 0.5f / sig;
      a2g[b] = 2.f * t2;
      g2n[b] = -t2 * (float)is;
    }
  } else {
    int i0 = (blk - 512) * 1024 + threadIdx.x * 4;   // 0..65532
    int half = i0 >> 15;
    int rem  = i0 & 32767;
    const float* src = half ? sw : mw;
    float4 f = *(const float4*)(src + rem);
    ((u32*)wb)[i0 >> 2] = pk_fp8(f.x, f.y, f.z, f.w);
  }
}

// ---------- main fused kernel ----------
__global__ __launch_bounds__(256, 2)
void policy_main(const float* __restrict__ obs,
                 const u8* __restrict__ Cb2,
                 const float* __restrict__ a2g,
                 const float* __restrict__ g2n,
                 const u8* __restrict__ wb,
                 const float* __restrict__ mbias,
                 const float* __restrict__ sbias,
                 float* __restrict__ out)
{
  // LDS: prologue obs i8 tile [0,16384) + x2p [16384,20736).
  // Epilogue red[4][64][68] f32 (69632 B) aliases from 0.
  __shared__ __align__(16) char smem[69888];
  float* x2p = (float*)(smem + 16384);
  float* red = (float*)smem;

  const int tid  = threadIdx.x;
  const int lane = tid & 63;
  const int wv   = tid >> 6;        // wave 0..3 : kc slice [16wv,16wv+16)
  const int c    = lane & 15;
  const int q    = lane >> 4;       // quad 0..3
  const int row0 = blockIdx.x * 64;
  const int kslc = 16 * wv + 4 * q; // lane's kc sub-slice base within tile
  const int cfo  = tid * 64;        // = wv*4096 + lane*64 : lane's fragment bytes

  // ---- prefetch pair 0 center fragments (tiles 0,1) into regs ----
  intx4 cfPA[4], cfPB[4], cfQA[4], cfQB[4];
  #pragma unroll
  for (int i = 0; i < 4; ++i) {
    cfPA[i] = *(const intx4*)(Cb2 + cfo + i * 16);
    cfPB[i] = *(const intx4*)(Cb2 + 16384 + cfo + i * 16);
  }

  // ---- convert obs tile fp32 -> i8 into LDS (XOR-swizzled 16B slots) + x2 ----
  #pragma unroll
  for (int i = 0; i < 4; ++i) {
    int s = i * 256 + tid;          // 16B slot 0..1023
    int row = s >> 4;
    int s16 = s & 15;
    int l16 = s16 ^ (row & 15);
    const float* src = obs + (size_t)(row0 + row) * 256 + l16 * 16;
    float4 f0 = ((const float4*)src)[0];
    float4 f1 = ((const float4*)src)[1];
    float4 f2 = ((const float4*)src)[2];
    float4 f3 = ((const float4*)src)[3];
    int a0 = q8(f0.x), a1v = q8(f0.y), a2v = q8(f0.z), a3 = q8(f0.w);
    int b0 = q8(f1.x), b1 = q8(f1.y), b2 = q8(f1.z), b3 = q8(f1.w);
    int c0 = q8(f2.x), c1 = q8(f2.y), c2 = q8(f2.z), c3 = q8(f2.w);
    int d0 = q8(f3.x), d1 = q8(f3.y), d2 = q8(f3.z), d3 = q8(f3.w);
    uint4 pk;
    pk.x = pk_i8(a0, a1v, a2v, a3);
    pk.y = pk_i8(b0, b1, b2, b3);
    pk.z = pk_i8(c0, c1, c2, c3);
    pk.w = pk_i8(d0, d1, d2, d3);
    *(uint4*)(smem + s * 16) = pk;
    int is = a0*a0 + a1v*a1v + a2v*a2v + a3*a3
           + b0*b0 + b1*b1 + b2*b2 + b3*b3
           + c0*c0 + c1*c1 + c2*c2 + c3*c3
           + d0*d0 + d1*d1 + d2*d2 + d3*d3;
    x2p[row * 16 + s16] = (float)is;
  }
  __syncthreads();   // obs tile + partials visible

  // ---- preload obs B-fragments: ob[nt][ks] = obs[b=nt*16+c][d=64ks+16q..+16] ----
  intx4 ob[4][4];                   // 64 regs (MFMA operands)
  #pragma unroll
  for (int nt = 0; nt < 4; ++nt) {
    const int row = nt * 16 + c;
    #pragma unroll
    for (int ks = 0; ks < 4; ++ks) {
      int slot = (4 * ks + q) ^ (row & 15);
      ob[nt][ks] = *(const intx4*)(smem + row * 256 + slot * 16);
    }
  }
  if (tid < 64) {
    float s = 0.f;
    #pragma unroll
    for (int j = 0; j < 16; j += 4) {
      float4 a = *(const float4*)(x2p + tid * 16 + j);
      s += a.x + a.y + a.z + a.w;
    }
    x2p[1024 + tid] = s;
  }
  __syncthreads();   // x2 sums visible (last barrier before epilogue)

  float hx2[4];
  #pragma unroll
  for (int nt = 0; nt < 4; ++nt) hx2[nt] = 0.5f * x2p[1024 + nt * 16 + c];

  const intx4 Z4i = {0, 0, 0, 0};
  const floatx4 Z4 = {0.f, 0.f, 0.f, 0.f};
  floatx4 acc2m[2][4], acc2s[2][4];   // 64 regs (AGPR), static indexing only
  #pragma unroll
  for (int a2i = 0; a2i < 2; ++a2i)
    #pragma unroll
    for (int nt = 0; nt < 4; ++nt) {
      acc2m[a2i][nt] = Z4;
      acc2s[a2i][nt] = Z4;
    }

  u32 pE[4], pc[4];

  // ---- K-loop: 16 pairs, NO barriers, NO LDS. CUR consumed, NXT prefetched. ----
#define PAIR_BODY(pr, CA, CB, NA, NB, ACC, HB)                                          \
  {                                                                                     \
    const int cte = 2 * (pr);                                                           \
    if ((pr) < 15) {                                                                    \
      const u8* g0 = Cb2 + (size_t)(cte + 2) * 16384 + cfo;                             \
      _Pragma("unroll")                                                                 \
      for (int i = 0; i < 4; ++i) {                                                     \
        NA[i] = *(const intx4*)(g0 + i * 16);                                           \
        NB[i] = *(const intx4*)(g0 + 16384 + i * 16);                                   \
      }                                                                                 \
    }                                                                                   \
    float4 a2e = *(const float4*)(a2g + cte * 64 + kslc);                               \
    float4 g2e = *(const float4*)(g2n + cte * 64 + kslc);                               \
    float4 a2o = *(const float4*)(a2g + cte * 64 + 64 + kslc);                          \
    float4 g2o = *(const float4*)(g2n + cte * 64 + 64 + kslc);                          \
    const int kbE = (cte & 15) * 64 + kslc;                                             \
    const u8* wr0 = wb + (size_t)((HB) + c) * 1024 + kbE;                               \
    const u8* wr1 = wb + (size_t)((HB) + 16 + c) * 1024 + kbE;                          \
    u32 w0lo = *(const u32*)wr0, w0hi = *(const u32*)(wr0 + 64);                        \
    u32 w1lo = *(const u32*)wr1, w1hi = *(const u32*)(wr1 + 64);                        \
    intx4 a1[4];                                                                        \
    a1[0] = __builtin_amdgcn_mfma_i32_16x16x64_i8(CA[0], ob[0][0], Z4i, 0, 0, 0);       \
    a1[1] = __builtin_amdgcn_mfma_i32_16x16x64_i8(CA[0], ob[1][0], Z4i, 0, 0, 0);       \
    a1[2] = __builtin_amdgcn_mfma_i32_16x16x64_i8(CA[0], ob[2][0], Z4i, 0, 0, 0);       \
    a1[3] = __builtin_amdgcn_mfma_i32_16x16x64_i8(CA[0], ob[3][0], Z4i, 0, 0, 0);       \
    _Pragma("unroll")                                                                   \
    for (int ks = 1; ks < 4; ++ks) {                                                    \
      a1[0] = __builtin_amdgcn_mfma_i32_16x16x64_i8(CA[ks], ob[0][ks], a1[0], 0, 0, 0); \
      a1[1] = __builtin_amdgcn_mfma_i32_16x16x64_i8(CA[ks], ob[1][ks], a1[1], 0, 0, 0); \
      a1[2] = __builtin_amdgcn_mfma_i32_16x16x64_i8(CA[ks], ob[2][ks], a1[2], 0, 0, 0); \
      a1[3] = __builtin_amdgcn_mfma_i32_16x16x64_i8(CA[ks], ob[3][ks], a1[3], 0, 0, 0); \
    }                                                                                   \
    _Pragma("unroll")                                                                   \
    for (int nt = 0; nt < 4; ++nt) {                                                    \
      float t0 = (float)a1[nt][0] - hx2[nt], t1 = (float)a1[nt][1] - hx2[nt];           \
      float t2 = (float)a1[nt][2] - hx2[nt], t3 = (float)a1[nt][3] - hx2[nt];           \
      pE[nt] = pk_fp8(__builtin_amdgcn_exp2f(fmaf(a2e.x, t0, g2e.x)),                   \
                      __builtin_amdgcn_exp2f(fmaf(a2e.y, t1, g2e.y)),                   \
                      __builtin_amdgcn_exp2f(fmaf(a2e.z, t2, g2e.z)),                   \
                      __builtin_amdgcn_exp2f(fmaf(a2e.w, t3, g2e.w)));                  \
    }                                                                                   \
    a1[0] = __builtin_amdgcn_mfma_i32_16x16x64_i8(CB[0], ob[0][0], Z4i, 0, 0, 0);       \
    a1[1] = __builtin_amdgcn_mfma_i32_16x16x64_i8(CB[0], ob[1][0], Z4i, 0, 0, 0);       \
    a1[2] = __builtin_amdgcn_mfma_i32_16x16x64_i8(CB[0], ob[2][0], Z4i, 0, 0, 0);       \
    a1[3] = __builtin_amdgcn_mfma_i32_16x16x64_i8(CB[0], ob[3][0], Z4i, 0, 0, 0);       \
    _Pragma("unroll")                                                                   \
    for (int ks = 1; ks < 4; ++ks) {                                                    \
      a1[0] = __builtin_amdgcn_mfma_i32_16x16x64_i8(CB[ks], ob[0][ks], a1[0], 0, 0, 0); \
      a1[1] = __builtin_amdgcn_mfma_i32_16x16x64_i8(CB[ks], ob[1][ks], a1[1], 0, 0, 0); \
      a1[2] = __builtin_amdgcn_mfma_i32_16x16x64_i8(CB[ks], ob[2][ks], a1[2], 0, 0, 0); \
      a1[3] = __builtin_amdgcn_mfma_i32_16x16x64_i8(CB[ks], ob[3][ks], a1[3], 0, 0, 0); \
    }                                                                                   \
    _Pragma("unroll")                                                                   \
    for (int nt = 0; nt < 4; ++nt) {                                                    \
      float t0 = (float)a1[nt][0] - hx2[nt], t1 = (float)a1[nt][1] - hx2[nt];           \
      float t2 = (float)a1[nt][2] - hx2[nt], t3 = (float)a1[nt][3] - hx2[nt];           \
      pc[nt] = pk_fp8(__builtin_amdgcn_exp2f(fmaf(a2o.x, t0, g2o.x)),                   \
                      __builtin_amdgcn_exp2f(fmaf(a2o.y, t1, g2o.y)),                   \
                      __builtin_amdgcn_exp2f(fmaf(a2o.z, t2, g2o.z)),                   \
                      __builtin_amdgcn_exp2f(fmaf(a2o.w, t3, g2o.w)));                  \
    }                                                                                   \
    { long wA0 = mk64(w0lo, w0hi), wA1 = mk64(w1lo, w1hi);                              \
      _Pragma("unroll")                                                                 \
      for (int nt = 0; nt < 4; ++nt) {                                                  \
        long pb = mk64(pE[nt], pc[nt]);                                                 \
        ACC[0][nt] = __builtin_amdgcn_mfma_f32_16x16x32_fp8_fp8(wA0, pb, ACC[0][nt], 0, 0, 0); \
        ACC[1][nt] = __builtin_amdgcn_mfma_f32_16x16x32_fp8_fp8(wA1, pb, ACC[1][nt], 0, 0, 0); \
      } }                                                                               \
  }

  for (int pr = 0; pr < 8; pr += 2) {
    PAIR_BODY(pr,     cfPA, cfPB, cfQA, cfQB, acc2m, 0)
    PAIR_BODY(pr + 1, cfQA, cfQB, cfPA, cfPB, acc2m, 0)
  }
  for (int pr = 8; pr < 16; pr += 2) {
    PAIR_BODY(pr,     cfPA, cfPB, cfQA, cfQB, acc2s, 32)
    PAIR_BODY(pr + 1, cfQA, cfQB, cfPA, cfPB, acc2s, 32)
  }
#undef PAIR_BODY

  // ---- epilogue: cross-wave reduction (red aliases obs LDS; K-loop reads no LDS) ----
  // red[wv][b=64][a=68pad]; lane(c,q) reg r holds a = h*32+a2i*16+4q+r, b = nt*16+c
  {
    float* myr = red + wv * 4352;
    #pragma unroll
    for (int a2i = 0; a2i < 2; ++a2i)
      #pragma unroll
      for (int nt = 0; nt < 4; ++nt) {
        *(floatx4*)(myr + (nt * 16 + c) * 68 + a2i * 16 + 4 * q)      = acc2m[a2i][nt];
        *(floatx4*)(myr + (nt * 16 + c) * 68 + 32 + a2i * 16 + 4 * q) = acc2s[a2i][nt];
      }
  }
  __syncthreads();

  #pragma unroll
  for (int i = 0; i < 16; ++i) {
    int idx = tid + 256 * i;        // 0..4095
    int a = idx & 63;
    int b = idx >> 6;
    float v = red[b * 68 + a] + red[4352 + b * 68 + a] +
              red[8704 + b * 68 + a] + red[13056 + b * 68 + a];
    if (a < 32) {
      v += mbias[a];
    } else {
      v += sbias[a - 32];
      v = fminf(fmaxf(v, -20.f), 2.f);
      v = __builtin_amdgcn_exp2f(v * LOG2E);
    }
    out[(size_t)(row0 + b) * 64 + a] = v;
  }
}

extern "C" void kernel_launch(void* const* d_in, const int* in_sizes, int n_in,
                              void* d_out, int out_size, void* d_ws, size_t ws_size,
                              hipStream_t stream) {
  const float* obs = (const float*)d_in[0];
  const float* mC  = (const float*)d_in[1];
  const float* mS  = (const float*)d_in[2];
  const float* mW  = (const float*)d_in[3];
  const float* mB  = (const float*)d_in[4];
  const float* sC  = (const float*)d_in[5];
  const float* sS  = (const float*)d_in[6];
  const float* sW  = (const float*)d_in[7];
  const float* sB  = (const float*)d_in[8];
  float* out = (float*)d_out;

  // workspace: Cb2[2048*256] i8 (512KB) | a2g[2048] f32 | g2n[2048] f32 | wb[65536] fp8
  u8*    Cb2 = (u8*)d_ws;
  float* a2g = (float*)((char*)d_ws + 2048 * 256);
  float* g2n = a2g + 2048;
  u8*    wb  = (u8*)(g2n + 2048);

  prep<<<576, 256, 0, stream>>>(mC, mS, sC, sS, mW, sW, Cb2, a2g, g2n, wb);
  policy_main<<<512, 256, 0, stream>>>(obs, Cb2, a2g, g2n, wb, mB, sB, out);
}